// Round 8
// baseline (704.561 us; speedup 1.0000x reference)
//
#include <hip/hip_runtime.h>

// HDC token encoder: out[b,i,d] = item_memory[token_ids[b,i]][(d - i) mod D] * 0.01f
// B=8, S=2048, V=256, D=10000. Every +/-1 row has L2 norm exactly 100, so the
// normalize is a constant scale by 0.01f (bit-exact vs reference, verified R0).
//
// R8: exact A/B vs R5 — plain vector stores instead of nontemporal. Theory:
// nt stores bypass L2 write-combining and cap at ~4.5 TB/s; the harness's
// 6.2 TB/s poison fill uses plain stores. Everything else identical to R5
// (two-phase: all 10 gather loads -> one wait -> 10-store burst, so no
// load-wait ever drains a store from the shared vmcnt FIFO).

#define B_ 8
#define S_ 2048
#define D_ 10000
#define NCH 10                           // ceil(2500 chunks / 256 threads)

typedef float vf4  __attribute__((ext_vector_type(4)));              // 16B aligned
typedef float vf4u __attribute__((ext_vector_type(4), aligned(4)));  // 4B aligned

__global__ __launch_bounds__(256) void hdc_encode(
    const int* __restrict__ token_ids,
    const float* __restrict__ item_memory,
    float* __restrict__ out)
{
    const int row = blockIdx.x;          // 0 .. B*S-1
    const int i   = row & (S_ - 1);      // shift amount (S is a power of two)
    const int tok = token_ids[row];      // block-uniform -> scalar load

    const float* __restrict__ src = item_memory + (size_t)tok * D_;
    float*       __restrict__ dst = out + (size_t)row * D_;

    const int tid = threadIdx.x;
    // chunks c = tid + 256*j, j in [0, nj); 2500 = 9*256 + 196
    const int nj = (tid < 2500 - 9 * 256) ? NCH : NCH - 1;

    // Phase 1: gather all chunks into registers. s_j = (4*tid - i + 1024*j) mod D.
    // Per thread at most ONE chunk crosses the row end (min circular gap of the
    // 10 offsets is 784 > 3), so the scalar wrap path runs once at most.
    vf4 v[NCH];
    int s = 4 * tid - i;
    if (s < 0) s += D_;
    #pragma unroll
    for (int j = 0; j < NCH; ++j) {
        if (j < nj) {
            if (s <= D_ - 4) {
                v[j] = *reinterpret_cast<const vf4u*>(src + s);  // 4B-aligned dwordx4
            } else {
                int s1 = s + 1; if (s1 >= D_) s1 -= D_;
                int s2 = s + 2; if (s2 >= D_) s2 -= D_;
                int s3 = s + 3; if (s3 >= D_) s3 -= D_;
                v[j].x = src[s]; v[j].y = src[s1]; v[j].z = src[s2]; v[j].w = src[s3];
            }
        }
        s += 1024;                        // 4 * 256
        if (s >= D_) s -= D_;
    }

    // Phase 2: store burst — plain stores (L2 write-combined), contiguous 1KB
    // per wave-instruction.
    vf4* __restrict__ dst4 = reinterpret_cast<vf4*>(dst);
    #pragma unroll
    for (int j = 0; j < NCH; ++j) {
        if (j < nj) {
            dst4[tid + 256 * j] = v[j] * 0.01f;
        }
    }
}

extern "C" void kernel_launch(void* const* d_in, const int* in_sizes, int n_in,
                              void* d_out, int out_size, void* d_ws, size_t ws_size,
                              hipStream_t stream)
{
    const int*   token_ids   = (const int*)d_in[0];
    const float* item_memory = (const float*)d_in[1];
    float*       out         = (float*)d_out;

    hdc_encode<<<dim3(B_ * S_), dim3(256), 0, stream>>>(token_ids, item_memory, out);
}

// Round 9
// 674.401 us; speedup vs baseline: 1.0447x; 1.0447x over previous
//
#include <hip/hip_runtime.h>

// HDC token encoder: out[b,i,d] = item_memory[token_ids[b,i]][(d - i) mod D] * 0.01f
// B=8, S=2048, V=256, D=10000. Every +/-1 row has L2 norm exactly 100, so the
// normalize is a constant scale by 0.01f (bit-exact vs reference, verified R0).
//
// FINAL (= R5, best of 8 variants at ~676 us total / ~145 us kernel):
// - two-phase per thread: all 10 independent gather loads -> one vmcnt wait ->
//   10-store burst, so no load-wait ever drains a store from the shared vmcnt
//   FIFO (R5 vs R4: -4 us; vs per-iter load/store R2: -26 us).
// - NONTEMPORAL stores: bypass L2 so the 655 MB write stream doesn't thrash
//   the L2-resident item_memory reads (R8 A/B: plain stores +29 us).
// - unaligned (4B-aligned) global_load_dwordx4 gathers: source phase (s mod 4)
//   is row-uniform; only the one row-end-crossing chunk takes the scalar path.
// Measured ceiling: 1.31 GB combined traffic in ~145 us = 9.0 TB/s, above the
// 6.29 TB/s float4-copy ceiling (reads are L2/L3-resident). Pipelining (R6),
// 8x read-volume collapse via token bucketing (R7), and store-policy (R8)
// all failed to beat this structure.

#define B_ 8
#define S_ 2048
#define D_ 10000
#define NCH 10                           // ceil(2500 chunks / 256 threads)

typedef float vf4  __attribute__((ext_vector_type(4)));              // 16B aligned
typedef float vf4u __attribute__((ext_vector_type(4), aligned(4)));  // 4B aligned

__global__ __launch_bounds__(256) void hdc_encode(
    const int* __restrict__ token_ids,
    const float* __restrict__ item_memory,
    float* __restrict__ out)
{
    const int row = blockIdx.x;          // 0 .. B*S-1
    const int i   = row & (S_ - 1);      // shift amount (S is a power of two)
    const int tok = token_ids[row];      // block-uniform -> scalar load

    const float* __restrict__ src = item_memory + (size_t)tok * D_;
    float*       __restrict__ dst = out + (size_t)row * D_;

    const int tid = threadIdx.x;
    // chunks c = tid + 256*j, j in [0, nj); 2500 = 9*256 + 196
    const int nj = (tid < 2500 - 9 * 256) ? NCH : NCH - 1;

    // Phase 1: gather all chunks into registers. s_j = (4*tid - i + 1024*j) mod D.
    // Per thread at most ONE chunk crosses the row end (min circular gap of the
    // 10 offsets is 784 > 3), so the scalar wrap path runs once at most.
    vf4 v[NCH];
    int s = 4 * tid - i;
    if (s < 0) s += D_;
    #pragma unroll
    for (int j = 0; j < NCH; ++j) {
        if (j < nj) {
            if (s <= D_ - 4) {
                v[j] = *reinterpret_cast<const vf4u*>(src + s);  // 4B-aligned dwordx4
            } else {
                int s1 = s + 1; if (s1 >= D_) s1 -= D_;
                int s2 = s + 2; if (s2 >= D_) s2 -= D_;
                int s3 = s + 3; if (s3 >= D_) s3 -= D_;
                v[j].x = src[s]; v[j].y = src[s1]; v[j].z = src[s2]; v[j].w = src[s3];
            }
        }
        s += 1024;                        // 4 * 256
        if (s >= D_) s -= D_;
    }

    // Phase 2: fire-and-forget nontemporal store burst (contiguous 1KB per
    // wave-instruction; never waited on).
    vf4* __restrict__ dst4 = reinterpret_cast<vf4*>(dst);
    #pragma unroll
    for (int j = 0; j < NCH; ++j) {
        if (j < nj) {
            __builtin_nontemporal_store(v[j] * 0.01f, dst4 + tid + 256 * j);
        }
    }
}

extern "C" void kernel_launch(void* const* d_in, const int* in_sizes, int n_in,
                              void* d_out, int out_size, void* d_ws, size_t ws_size,
                              hipStream_t stream)
{
    const int*   token_ids   = (const int*)d_in[0];
    const float* item_memory = (const float*)d_in[1];
    float*       out         = (float*)d_out;

    hdc_encode<<<dim3(B_ * S_), dim3(256), 0, stream>>>(token_ids, item_memory, out);
}